// Round 6
// baseline (39.311 us; speedup 1.0000x reference)
//
#include <hip/hip_runtime.h>
#include <stdint.h>

// BLS12-377 Fr: p = 0x12ab655e9a2ca55660b44d1e5c37b00159aa76fed00000010a11800000000001
//
// Reference computes (a*R mod p + b*R mod p) mod p, canonical in [0,p), R = 2^256.
// Inputs a,b each have 4 64-bit limbs < 2^31 (values < 2^223), so a+b < 2^224 < p and
// the result equals (a+b)*R mod p. With s_k = a_k + b_k (< 2^32, no inter-limb carry),
// result = (sum_k s_k * D_k) * 2^-64 mod p where D_k = 2^(320+64k) mod p.
//
// Bounds: T0 = sum s_k*D_k < 2^34*p (9 limbs, limb8 < 2^31).
//   REDC step 1: T1 < 5p < 2^255  (8 limbs, top < 2^31)
//   REDC step 2: T2 < 2p          (single cond_sub -> canonical, bit-exact vs ref)
//
// Harness dtypes: inputs int32[N*4] (limbs < 2^31), output int32[N*4] = low 32 bits
// of each 64-bit output word = even 32-bit limbs of the canonical residue.
//
// Round 6: latency-bound diagnosis (VALUBusy ~50%, BW ~58% achievable, occupancy
// ~62% -- nothing saturated). Grid-stride loop, 8 elements/thread, with next
// element's loads issued BEFORE current element's ~500-cycle mad chain (T14
// issue-early). Output stored non-temporally (never re-read) to keep L3 for
// inputs. Single-element math unchanged from Round 3 (best so far; rounds 4-5
// showed the compiler serializes any 2-chain variant).

#define MASK32 0xffffffffull

typedef int v4i __attribute__((ext_vector_type(4)));

namespace {

constexpr uint32_t PL[8] = {
  0x00000001u, 0x0a118000u, 0xd0000001u, 0x59aa76feu,
  0x5c37b001u, 0x60b44d1eu, 0x9a2ca556u, 0x12ab655eu
};

struct U256 { uint32_t l[8]; };

constexpr bool geq_p(const U256& x) {
  for (int i = 7; i >= 0; --i) {
    if (x.l[i] != PL[i]) return x.l[i] > PL[i];
  }
  return true;  // equal
}

// 2^e mod p via double-and-reduce from 2^252 (< p since p > 2^252).
constexpr U256 pow2_mod(int e) {
  U256 x{};
  for (int i = 0; i < 8; ++i) x.l[i] = 0;
  x.l[7] = 0x10000000u;  // 2^252
  for (int it = 0; it < e - 252; ++it) {
    uint32_t carry = 0;
    for (int j = 0; j < 8; ++j) {
      uint32_t nc = x.l[j] >> 31;
      x.l[j] = (x.l[j] << 1) | carry;
      carry = nc;
    }
    if (geq_p(x)) {
      uint64_t borrow = 0;
      for (int j = 0; j < 8; ++j) {
        uint64_t d = (uint64_t)x.l[j] - (uint64_t)PL[j] - borrow;
        x.l[j] = (uint32_t)d;
        borrow = (d >> 32) & 1ull;
      }
    }
  }
  return x;
}

constexpr U256 D0 = pow2_mod(320);
constexpr U256 D1 = pow2_mod(384);
constexpr U256 D2 = pow2_mod(448);
constexpr U256 D3 = pow2_mod(512);

}  // namespace

__device__ __forceinline__ v4i fr_tomont_add_one(const v4i av, const v4i bv) {
  // s_k = a_k + b_k, each input limb < 2^31 so the 32-bit sum cannot overflow
  uint32_t s0 = (uint32_t)av.x + (uint32_t)bv.x;
  uint32_t s1 = (uint32_t)av.y + (uint32_t)bv.y;
  uint32_t s2 = (uint32_t)av.z + (uint32_t)bv.z;
  uint32_t s3 = (uint32_t)av.w + (uint32_t)bv.w;

  uint64_t t[8];
  uint32_t t8;

  // Row 0: t = s0 * D0  (no accumulate)
  {
    uint64_t c = 0;
#pragma unroll
    for (int j = 0; j < 8; ++j) {
      uint64_t x = (uint64_t)s0 * (uint64_t)D0.l[j] + c;
      t[j] = x & MASK32;
      c = x >> 32;
    }
    t8 = (uint32_t)c;
  }

  // Rows 1..3: t += s_k * D_k   (t8 < 2^31 throughout since T0 < 2^287)
  {
    const uint32_t* Dk[3] = {D1.l, D2.l, D3.l};
    const uint32_t sk[3] = {s1, s2, s3};
#pragma unroll
    for (int k = 0; k < 3; ++k) {
      uint64_t c = 0;
#pragma unroll
      for (int j = 0; j < 8; ++j) {
        uint64_t x = t[j] + (uint64_t)sk[k] * (uint64_t)Dk[k][j] + c;
        t[j] = x & MASK32;
        c = x >> 32;
      }
      t8 += (uint32_t)c;
    }
  }

  // REDC step 1 (9 limbs -> 8): m = -t0 mod 2^32 (p[0] == 1)
  {
    uint32_t m = (uint32_t)0u - (uint32_t)t[0];
    uint64_t x0 = t[0] + (uint64_t)m;   // == 0 or 2^32
    uint64_t c = x0 >> 32;
#pragma unroll
    for (int j = 1; j < 8; ++j) {
      uint64_t x = t[j] + (uint64_t)m * (uint64_t)PL[j] + c;
      t[j - 1] = x & MASK32;
      c = x >> 32;
    }
    // T1 < 5p < 2^255 -> true limb7 = t8 + c < 2^31, no overflow
    t[7] = (uint64_t)(t8 + (uint32_t)c);
  }

  // REDC step 2 (8 limbs): T2 < 2p
  {
    uint32_t m = (uint32_t)0u - (uint32_t)t[0];
    uint64_t x0 = t[0] + (uint64_t)m;
    uint64_t c = x0 >> 32;
#pragma unroll
    for (int j = 1; j < 8; ++j) {
      uint64_t x = t[j] + (uint64_t)m * (uint64_t)PL[j] + c;
      t[j - 1] = x & MASK32;
      c = x >> 32;
    }
    t[7] = c;  // top limb of T2 < 2p, fits 32 bits
  }

  // cond_sub: T2 < 2p, subtract p iff t >= p (no borrow) -> canonical residue
  uint32_t d[8];
  uint64_t borrow = 0;
#pragma unroll
  for (int j = 0; j < 8; ++j) {
    uint64_t x = t[j] - (uint64_t)PL[j] - borrow;
    d[j] = (uint32_t)x;
    borrow = (x >> 32) & 1ull;
  }
  bool use = (borrow == 0);
  v4i o;
  o.x = (int)(use ? d[0] : (uint32_t)t[0]);
  o.y = (int)(use ? d[2] : (uint32_t)t[2]);
  o.z = (int)(use ? d[4] : (uint32_t)t[4]);
  o.w = (int)(use ? d[6] : (uint32_t)t[6]);
  return o;
}

__global__ __launch_bounds__(256, 8) void fr_tomont_add_kernel(
    const v4i* __restrict__ in1,
    const v4i* __restrict__ in2,
    v4i* __restrict__ out,
    int n) {
  int i = blockIdx.x * blockDim.x + threadIdx.x;
  int stride = gridDim.x * blockDim.x;
  if (i >= n) return;

  // Prime the pipeline: current element's inputs.
  v4i a = in1[i];
  v4i b = in2[i];

  for (;;) {
    int next = i + stride;
    bool more = next < n;
    v4i an, bn;
    if (more) {
      // Prefetch next element BEFORE the ~500-cycle mad chain below; the
      // compiler keeps these loads in flight across the compute (uses are
      // after the store), so HBM latency hides under VALU work.
      an = in1[next];
      bn = in2[next];
    }

    v4i o = fr_tomont_add_one(a, b);
    // Non-temporal store: output is never re-read; keep L3 for inputs.
    __builtin_nontemporal_store(o, out + i);

    if (!more) break;
    i = next;
    a = an;
    b = bn;
  }
}

extern "C" void kernel_launch(void* const* d_in, const int* in_sizes, int n_in,
                              void* d_out, int out_size, void* d_ws, size_t ws_size,
                              hipStream_t stream) {
  const v4i* in1 = (const v4i*)d_in[0];
  const v4i* in2 = (const v4i*)d_in[1];
  v4i* out = (v4i*)d_out;
  int n = in_sizes[0] / 4;  // (N,4) -> N elements

  const int block = 256;
  const int elems_per_thread = 8;
  int grid = (n + block * elems_per_thread - 1) / (block * elems_per_thread);
  fr_tomont_add_kernel<<<grid, block, 0, stream>>>(in1, in2, out, n);
}

// Round 7
// 37.926 us; speedup vs baseline: 1.0365x; 1.0365x over previous
//
#include <hip/hip_runtime.h>
#include <stdint.h>

// BLS12-377 Fr: p = 0x12ab655e9a2ca55660b44d1e5c37b00159aa76fed00000010a11800000000001
//
// Reference computes (a*R mod p + b*R mod p) mod p, canonical in [0,p), R = 2^256.
// Inputs a,b each have 4 64-bit limbs < 2^31 (values < 2^223), so a+b < 2^224 < p and
// the result equals (a+b)*R mod p. With s_k = a_k + b_k (< 2^32, no inter-limb carry),
// result = (sum_k s_k * D_k) * 2^-64 mod p where D_k = 2^(320+64k) mod p.
//
// Bounds: T0 = sum s_k*D_k < 2^34*p (9 limbs, limb8 < 2^31).
//   REDC step 1: T1 < 5p < 2^255  (8 limbs, top < 2^31)
//   REDC step 2: T2 < 2p          (single cond_sub -> canonical, bit-exact vs ref)
//
// Harness dtypes: inputs int32[N*4] (limbs < 2^31), output int32[N*4] = low 32 bits
// of each 64-bit output word = even 32-bit limbs of the canonical residue.
//
// Round 7: rounds 4-6 showed the pre-RA scheduler serializes independent chains to
// minimize VGPR pressure (VGPR stayed 32/24; ILP never materialized). This round
// forces a 2-element interleave with __builtin_amdgcn_sched_barrier(0) after each
// A/B statement pair: each scheduling region holds one step of chain A and one of
// chain B, so both chains stay live across the whole kernel and chain B's mads
// fill chain A's latency slots. launch_bounds(256,6) gives regalloc headroom
// (<=85 VGPR) while keeping >=6 waves/SIMD.

#define MASK32 0xffffffffull
#define SB() __builtin_amdgcn_sched_barrier(0)

namespace {

constexpr uint32_t PL[8] = {
  0x00000001u, 0x0a118000u, 0xd0000001u, 0x59aa76feu,
  0x5c37b001u, 0x60b44d1eu, 0x9a2ca556u, 0x12ab655eu
};

struct U256 { uint32_t l[8]; };

constexpr bool geq_p(const U256& x) {
  for (int i = 7; i >= 0; --i) {
    if (x.l[i] != PL[i]) return x.l[i] > PL[i];
  }
  return true;  // equal
}

// 2^e mod p via double-and-reduce from 2^252 (< p since p > 2^252).
constexpr U256 pow2_mod(int e) {
  U256 x{};
  for (int i = 0; i < 8; ++i) x.l[i] = 0;
  x.l[7] = 0x10000000u;  // 2^252
  for (int it = 0; it < e - 252; ++it) {
    uint32_t carry = 0;
    for (int j = 0; j < 8; ++j) {
      uint32_t nc = x.l[j] >> 31;
      x.l[j] = (x.l[j] << 1) | carry;
      carry = nc;
    }
    if (geq_p(x)) {
      uint64_t borrow = 0;
      for (int j = 0; j < 8; ++j) {
        uint64_t d = (uint64_t)x.l[j] - (uint64_t)PL[j] - borrow;
        x.l[j] = (uint32_t)d;
        borrow = (d >> 32) & 1ull;
      }
    }
  }
  return x;
}

constexpr U256 D0 = pow2_mod(320);
constexpr U256 D1 = pow2_mod(384);
constexpr U256 D2 = pow2_mod(448);
constexpr U256 D3 = pow2_mod(512);

}  // namespace

__global__ __launch_bounds__(256, 6) void fr_tomont_add_kernel(
    const int4* __restrict__ in1,
    const int4* __restrict__ in2,
    int4* __restrict__ out,
    int half) {
  int idx = blockIdx.x * blockDim.x + threadIdx.x;
  if (idx >= half) return;
  int idxB = idx + half;

  // All 4 loads issue together (memory parallelism); each is lane-contiguous.
  int4 avA = in1[idx];
  int4 bvA = in2[idx];
  int4 avB = in1[idxB];
  int4 bvB = in2[idxB];

  // s_k = a_k + b_k; input limbs < 2^31 so no 32-bit overflow.
  uint32_t sA[4] = { (uint32_t)avA.x + (uint32_t)bvA.x,
                     (uint32_t)avA.y + (uint32_t)bvA.y,
                     (uint32_t)avA.z + (uint32_t)bvA.z,
                     (uint32_t)avA.w + (uint32_t)bvA.w };
  uint32_t sB[4] = { (uint32_t)avB.x + (uint32_t)bvB.x,
                     (uint32_t)avB.y + (uint32_t)bvB.y,
                     (uint32_t)avB.z + (uint32_t)bvB.z,
                     (uint32_t)avB.w + (uint32_t)bvB.w };

  uint64_t tA[8], tB[8];
  uint32_t t8A, t8B;

  // ---- Row 0: t = s0 * D0 (no accumulate); A/B pair per scheduling region ----
  {
    uint64_t cA = 0, cB = 0;
#pragma unroll
    for (int j = 0; j < 8; ++j) {
      uint64_t xA = (uint64_t)sA[0] * (uint64_t)D0.l[j] + cA;
      uint64_t xB = (uint64_t)sB[0] * (uint64_t)D0.l[j] + cB;
      tA[j] = xA & MASK32;  cA = xA >> 32;
      tB[j] = xB & MASK32;  cB = xB >> 32;
      SB();
    }
    t8A = (uint32_t)cA;
    t8B = (uint32_t)cB;
  }

  // ---- Rows 1..3: t += s_k * D_k (t8 < 2^31 throughout) ----
  {
    const uint32_t* Dk[3] = {D1.l, D2.l, D3.l};
#pragma unroll
    for (int k = 0; k < 3; ++k) {
      uint64_t cA = 0, cB = 0;
#pragma unroll
      for (int j = 0; j < 8; ++j) {
        uint64_t xA = tA[j] + (uint64_t)sA[k + 1] * (uint64_t)Dk[k][j] + cA;
        uint64_t xB = tB[j] + (uint64_t)sB[k + 1] * (uint64_t)Dk[k][j] + cB;
        tA[j] = xA & MASK32;  cA = xA >> 32;
        tB[j] = xB & MASK32;  cB = xB >> 32;
        SB();
      }
      t8A += (uint32_t)cA;
      t8B += (uint32_t)cB;
    }
  }

  // ---- REDC step 1 (9 limbs -> 8): m = -t0 mod 2^32 (p[0] == 1) ----
  {
    uint32_t mA = (uint32_t)0u - (uint32_t)tA[0];
    uint32_t mB = (uint32_t)0u - (uint32_t)tB[0];
    uint64_t x0A = tA[0] + (uint64_t)mA;  // == 0 or 2^32; carry = x0 >> 32
    uint64_t x0B = tB[0] + (uint64_t)mB;
    uint64_t cA = x0A >> 32;
    uint64_t cB = x0B >> 32;
    SB();
#pragma unroll
    for (int j = 1; j < 8; ++j) {
      uint64_t xA = tA[j] + (uint64_t)mA * (uint64_t)PL[j] + cA;
      uint64_t xB = tB[j] + (uint64_t)mB * (uint64_t)PL[j] + cB;
      tA[j - 1] = xA & MASK32;  cA = xA >> 32;
      tB[j - 1] = xB & MASK32;  cB = xB >> 32;
      SB();
    }
    // T1 < 5p < 2^255: true limb7 = t8 + c < 2^31, no overflow
    tA[7] = (uint64_t)(t8A + (uint32_t)cA);
    tB[7] = (uint64_t)(t8B + (uint32_t)cB);
  }

  // ---- REDC step 2 (8 limbs): T2 < 2p ----
  {
    uint32_t mA = (uint32_t)0u - (uint32_t)tA[0];
    uint32_t mB = (uint32_t)0u - (uint32_t)tB[0];
    uint64_t x0A = tA[0] + (uint64_t)mA;
    uint64_t x0B = tB[0] + (uint64_t)mB;
    uint64_t cA = x0A >> 32;
    uint64_t cB = x0B >> 32;
    SB();
#pragma unroll
    for (int j = 1; j < 8; ++j) {
      uint64_t xA = tA[j] + (uint64_t)mA * (uint64_t)PL[j] + cA;
      uint64_t xB = tB[j] + (uint64_t)mB * (uint64_t)PL[j] + cB;
      tA[j - 1] = xA & MASK32;  cA = xA >> 32;
      tB[j - 1] = xB & MASK32;  cB = xB >> 32;
      SB();
    }
    tA[7] = cA;  // top limb of T2 < 2p fits 32 bits
    tB[7] = cB;
  }

  // ---- cond_sub: subtract p iff t >= p (no borrow) -> canonical ----
  uint32_t dA[8], dB[8];
  {
    uint64_t brA = 0, brB = 0;
#pragma unroll
    for (int j = 0; j < 8; ++j) {
      uint64_t xA = tA[j] - (uint64_t)PL[j] - brA;
      uint64_t xB = tB[j] - (uint64_t)PL[j] - brB;
      dA[j] = (uint32_t)xA;  brA = (xA >> 32) & 1ull;
      dB[j] = (uint32_t)xB;  brB = (xB >> 32) & 1ull;
      SB();
    }
    bool useA = (brA == 0);
    bool useB = (brB == 0);
    // Output int32 = low 32 bits of each 64-bit word = even 32-bit limbs.
    int4 oA = make_int4((int)(useA ? dA[0] : (uint32_t)tA[0]),
                        (int)(useA ? dA[2] : (uint32_t)tA[2]),
                        (int)(useA ? dA[4] : (uint32_t)tA[4]),
                        (int)(useA ? dA[6] : (uint32_t)tA[6]));
    int4 oB = make_int4((int)(useB ? dB[0] : (uint32_t)tB[0]),
                        (int)(useB ? dB[2] : (uint32_t)tB[2]),
                        (int)(useB ? dB[4] : (uint32_t)tB[4]),
                        (int)(useB ? dB[6] : (uint32_t)tB[6]));
    out[idx] = oA;
    out[idxB] = oB;
  }
}

extern "C" void kernel_launch(void* const* d_in, const int* in_sizes, int n_in,
                              void* d_out, int out_size, void* d_ws, size_t ws_size,
                              hipStream_t stream) {
  const int4* in1 = (const int4*)d_in[0];
  const int4* in2 = (const int4*)d_in[1];
  int4* out = (int4*)d_out;
  int n = in_sizes[0] / 4;   // (N,4) -> N elements
  int half = n / 2;          // N = 4194304, even

  const int block = 256;
  const int grid = (half + block - 1) / block;
  fr_tomont_add_kernel<<<grid, block, 0, stream>>>(in1, in2, out, half);
}

// Round 8
// 34.310 us; speedup vs baseline: 1.1458x; 1.1054x over previous
//
#include <hip/hip_runtime.h>
#include <stdint.h>

// BLS12-377 Fr: p = 0x12ab655e9a2ca55660b44d1e5c37b00159aa76fed00000010a11800000000001
//
// Reference computes (a*R mod p + b*R mod p) mod p, canonical in [0,p), R = 2^256.
// Inputs a,b each have 4 64-bit limbs < 2^31 (values < 2^223), so a+b < 2^224 < p and
// the result equals (a+b)*R mod p. With s_k = a_k + b_k (< 2^32, no inter-limb carry),
// result = (sum_k s_k * D_k) * 2^-64 mod p where D_k = 2^(320+64k) mod p.
//
// Bounds: T0 = sum s_k*D_k < 2^34*p (9 limbs, limb8 < 2^31).
//   REDC step 1: T1 < 5p < 2^255  (8 limbs, top < 2^31)
//   REDC step 2: T2 < 2p          (single cond_sub -> canonical, bit-exact vs ref)
//
// Harness dtypes: inputs int32[N*4] (limbs < 2^31), output int32[N*4] = low 32 bits
// of each 64-bit output word = even 32-bit limbs of the canonical residue.
//
// Round 8: instruction diet. Rounds 4-7 proved thread-level ILP is unreachable
// from source (compiler serializes; VGPR stayed 24-32). Measured VALU busy-time
// (~27 us) is ~2x the ideal instruction arithmetic (~13 us), pointing at codegen
// fat from uint64_t-typed persistent state (zero-extended high words, 64-bit
// moves/adds). This version keeps ALL persistent state in uint32_t scalars;
// 64-bit values exist only transiently inside (uint64)s*D + c expressions
// (one v_mad_u64_u32 each). Config otherwise identical to Round 3 (best: 35.4us):
// 1 element/thread, plain launch_bounds(256). Output via non-temporal store.

#define MASK32 0xffffffffull

namespace {

constexpr uint32_t PL[8] = {
  0x00000001u, 0x0a118000u, 0xd0000001u, 0x59aa76feu,
  0x5c37b001u, 0x60b44d1eu, 0x9a2ca556u, 0x12ab655eu
};

struct U256 { uint32_t l[8]; };

constexpr bool geq_p(const U256& x) {
  for (int i = 7; i >= 0; --i) {
    if (x.l[i] != PL[i]) return x.l[i] > PL[i];
  }
  return true;  // equal
}

// 2^e mod p via double-and-reduce from 2^252 (< p since p > 2^252).
constexpr U256 pow2_mod(int e) {
  U256 x{};
  for (int i = 0; i < 8; ++i) x.l[i] = 0;
  x.l[7] = 0x10000000u;  // 2^252
  for (int it = 0; it < e - 252; ++it) {
    uint32_t carry = 0;
    for (int j = 0; j < 8; ++j) {
      uint32_t nc = x.l[j] >> 31;
      x.l[j] = (x.l[j] << 1) | carry;
      carry = nc;
    }
    if (geq_p(x)) {
      uint64_t borrow = 0;
      for (int j = 0; j < 8; ++j) {
        uint64_t d = (uint64_t)x.l[j] - (uint64_t)PL[j] - borrow;
        x.l[j] = (uint32_t)d;
        borrow = (d >> 32) & 1ull;
      }
    }
  }
  return x;
}

constexpr U256 D0 = pow2_mod(320);
constexpr U256 D1 = pow2_mod(384);
constexpr U256 D2 = pow2_mod(448);
constexpr U256 D3 = pow2_mod(512);

}  // namespace

typedef int v4i __attribute__((ext_vector_type(4)));

__global__ __launch_bounds__(256) void fr_tomont_add_kernel(
    const v4i* __restrict__ in1,
    const v4i* __restrict__ in2,
    v4i* __restrict__ out,
    int n) {
  int idx = blockIdx.x * blockDim.x + threadIdx.x;
  if (idx >= n) return;

  v4i av = in1[idx];
  v4i bv = in2[idx];

  // s_k = a_k + b_k; input limbs < 2^31 so the 32-bit sum cannot overflow.
  uint32_t s0 = (uint32_t)av.x + (uint32_t)bv.x;
  uint32_t s1 = (uint32_t)av.y + (uint32_t)bv.y;
  uint32_t s2 = (uint32_t)av.z + (uint32_t)bv.z;
  uint32_t s3 = (uint32_t)av.w + (uint32_t)bv.w;

  // All persistent state is 32-bit; x is the only 64-bit temp.
  uint32_t t0, t1, t2, t3, t4, t5, t6, t7, t8;
  uint64_t x;
  uint32_t c;

  // ---- Row 0: t = s0 * D0 ----
  x = (uint64_t)s0 * D0.l[0];            t0 = (uint32_t)x; c = (uint32_t)(x >> 32);
  x = (uint64_t)s0 * D0.l[1] + c;        t1 = (uint32_t)x; c = (uint32_t)(x >> 32);
  x = (uint64_t)s0 * D0.l[2] + c;        t2 = (uint32_t)x; c = (uint32_t)(x >> 32);
  x = (uint64_t)s0 * D0.l[3] + c;        t3 = (uint32_t)x; c = (uint32_t)(x >> 32);
  x = (uint64_t)s0 * D0.l[4] + c;        t4 = (uint32_t)x; c = (uint32_t)(x >> 32);
  x = (uint64_t)s0 * D0.l[5] + c;        t5 = (uint32_t)x; c = (uint32_t)(x >> 32);
  x = (uint64_t)s0 * D0.l[6] + c;        t6 = (uint32_t)x; c = (uint32_t)(x >> 32);
  x = (uint64_t)s0 * D0.l[7] + c;        t7 = (uint32_t)x; t8 = (uint32_t)(x >> 32);

  // ---- Row 1: t += s1 * D1 ----
  x = (uint64_t)s1 * D1.l[0] + t0;       t0 = (uint32_t)x; c = (uint32_t)(x >> 32);
  x = (uint64_t)s1 * D1.l[1] + t1 + c;   t1 = (uint32_t)x; c = (uint32_t)(x >> 32);
  x = (uint64_t)s1 * D1.l[2] + t2 + c;   t2 = (uint32_t)x; c = (uint32_t)(x >> 32);
  x = (uint64_t)s1 * D1.l[3] + t3 + c;   t3 = (uint32_t)x; c = (uint32_t)(x >> 32);
  x = (uint64_t)s1 * D1.l[4] + t4 + c;   t4 = (uint32_t)x; c = (uint32_t)(x >> 32);
  x = (uint64_t)s1 * D1.l[5] + t5 + c;   t5 = (uint32_t)x; c = (uint32_t)(x >> 32);
  x = (uint64_t)s1 * D1.l[6] + t6 + c;   t6 = (uint32_t)x; c = (uint32_t)(x >> 32);
  x = (uint64_t)s1 * D1.l[7] + t7 + c;   t7 = (uint32_t)x; t8 += (uint32_t)(x >> 32);

  // ---- Row 2: t += s2 * D2 ----
  x = (uint64_t)s2 * D2.l[0] + t0;       t0 = (uint32_t)x; c = (uint32_t)(x >> 32);
  x = (uint64_t)s2 * D2.l[1] + t1 + c;   t1 = (uint32_t)x; c = (uint32_t)(x >> 32);
  x = (uint64_t)s2 * D2.l[2] + t2 + c;   t2 = (uint32_t)x; c = (uint32_t)(x >> 32);
  x = (uint64_t)s2 * D2.l[3] + t3 + c;   t3 = (uint32_t)x; c = (uint32_t)(x >> 32);
  x = (uint64_t)s2 * D2.l[4] + t4 + c;   t4 = (uint32_t)x; c = (uint32_t)(x >> 32);
  x = (uint64_t)s2 * D2.l[5] + t5 + c;   t5 = (uint32_t)x; c = (uint32_t)(x >> 32);
  x = (uint64_t)s2 * D2.l[6] + t6 + c;   t6 = (uint32_t)x; c = (uint32_t)(x >> 32);
  x = (uint64_t)s2 * D2.l[7] + t7 + c;   t7 = (uint32_t)x; t8 += (uint32_t)(x >> 32);

  // ---- Row 3: t += s3 * D3 ----
  x = (uint64_t)s3 * D3.l[0] + t0;       t0 = (uint32_t)x; c = (uint32_t)(x >> 32);
  x = (uint64_t)s3 * D3.l[1] + t1 + c;   t1 = (uint32_t)x; c = (uint32_t)(x >> 32);
  x = (uint64_t)s3 * D3.l[2] + t2 + c;   t2 = (uint32_t)x; c = (uint32_t)(x >> 32);
  x = (uint64_t)s3 * D3.l[3] + t3 + c;   t3 = (uint32_t)x; c = (uint32_t)(x >> 32);
  x = (uint64_t)s3 * D3.l[4] + t4 + c;   t4 = (uint32_t)x; c = (uint32_t)(x >> 32);
  x = (uint64_t)s3 * D3.l[5] + t5 + c;   t5 = (uint32_t)x; c = (uint32_t)(x >> 32);
  x = (uint64_t)s3 * D3.l[6] + t6 + c;   t6 = (uint32_t)x; c = (uint32_t)(x >> 32);
  x = (uint64_t)s3 * D3.l[7] + t7 + c;   t7 = (uint32_t)x; t8 += (uint32_t)(x >> 32);

  // ---- REDC step 1 (9 -> 8 limbs): m = -t0 mod 2^32 (p[0] == 1) ----
  {
    uint32_t m = 0u - t0;
    c = (t0 != 0u) ? 1u : 0u;            // carry of t0 + m*1
    x = (uint64_t)m * PL[1] + t1 + c;    t0 = (uint32_t)x; c = (uint32_t)(x >> 32);
    x = (uint64_t)m * PL[2] + t2 + c;    t1 = (uint32_t)x; c = (uint32_t)(x >> 32);
    x = (uint64_t)m * PL[3] + t3 + c;    t2 = (uint32_t)x; c = (uint32_t)(x >> 32);
    x = (uint64_t)m * PL[4] + t4 + c;    t3 = (uint32_t)x; c = (uint32_t)(x >> 32);
    x = (uint64_t)m * PL[5] + t5 + c;    t4 = (uint32_t)x; c = (uint32_t)(x >> 32);
    x = (uint64_t)m * PL[6] + t6 + c;    t5 = (uint32_t)x; c = (uint32_t)(x >> 32);
    x = (uint64_t)m * PL[7] + t7 + c;    t6 = (uint32_t)x; c = (uint32_t)(x >> 32);
    t7 = t8 + c;                          // T1 < 5p < 2^255: no overflow
  }

  // ---- REDC step 2 (8 limbs): T2 < 2p ----
  {
    uint32_t m = 0u - t0;
    c = (t0 != 0u) ? 1u : 0u;
    x = (uint64_t)m * PL[1] + t1 + c;    t0 = (uint32_t)x; c = (uint32_t)(x >> 32);
    x = (uint64_t)m * PL[2] + t2 + c;    t1 = (uint32_t)x; c = (uint32_t)(x >> 32);
    x = (uint64_t)m * PL[3] + t3 + c;    t2 = (uint32_t)x; c = (uint32_t)(x >> 32);
    x = (uint64_t)m * PL[4] + t4 + c;    t3 = (uint32_t)x; c = (uint32_t)(x >> 32);
    x = (uint64_t)m * PL[5] + t5 + c;    t4 = (uint32_t)x; c = (uint32_t)(x >> 32);
    x = (uint64_t)m * PL[6] + t6 + c;    t5 = (uint32_t)x; c = (uint32_t)(x >> 32);
    x = (uint64_t)m * PL[7] + t7 + c;    t6 = (uint32_t)x; t7 = (uint32_t)(x >> 32);
  }

  // ---- cond_sub: T2 < 2p; subtract p iff no borrow -> canonical residue ----
  uint32_t d0, d2, d4, d6;
  {
    uint64_t y;
    y = (uint64_t)t0 - PL[0];                          d0 = (uint32_t)y;
    y = (uint64_t)t1 - PL[1] - ((y >> 32) & 1ull);     /* d1 */
    y = (uint64_t)t2 - PL[2] - ((y >> 32) & 1ull);     d2 = (uint32_t)y;
    y = (uint64_t)t3 - PL[3] - ((y >> 32) & 1ull);     /* d3 */
    y = (uint64_t)t4 - PL[4] - ((y >> 32) & 1ull);     d4 = (uint32_t)y;
    y = (uint64_t)t5 - PL[5] - ((y >> 32) & 1ull);     /* d5 */
    y = (uint64_t)t6 - PL[6] - ((y >> 32) & 1ull);     d6 = (uint32_t)y;
    y = (uint64_t)t7 - PL[7] - ((y >> 32) & 1ull);
    bool use = (((y >> 32) & 1ull) == 0);              // no final borrow -> t >= p
    v4i o;
    o.x = (int)(use ? d0 : t0);
    o.y = (int)(use ? d2 : t2);
    o.z = (int)(use ? d4 : t4);
    o.w = (int)(use ? d6 : t6);
    // Non-temporal store: output never re-read.
    __builtin_nontemporal_store(o, out + idx);
  }
}

extern "C" void kernel_launch(void* const* d_in, const int* in_sizes, int n_in,
                              void* d_out, int out_size, void* d_ws, size_t ws_size,
                              hipStream_t stream) {
  const v4i* in1 = (const v4i*)d_in[0];
  const v4i* in2 = (const v4i*)d_in[1];
  v4i* out = (v4i*)d_out;
  int n = in_sizes[0] / 4;  // (N,4) -> N elements

  const int block = 256;
  const int grid = (n + block - 1) / block;
  fr_tomont_add_kernel<<<grid, block, 0, stream>>>(in1, in2, out, n);
}